// Round 7
// baseline (267.645 us; speedup 1.0000x reference)
//
#include <hip/hip_runtime.h>

#define NEG_SLOPE 0.2f
#define NPB 256          // nodes per dst-bucket (bucket = dst >> 8)
#define CHUNK 4096       // edges per partition block
#define BCAP 5120        // padded bucket capacity (expected fill 4096, +16 sigma)

typedef _Float16 f16x8 __attribute__((ext_vector_type(8)));
typedef _Float16 f16x4 __attribute__((ext_vector_type(4)));
typedef _Float16 f16x2 __attribute__((ext_vector_type(2)));
typedef float    f32x4 __attribute__((ext_vector_type(4)));
typedef float    f32x8 __attribute__((ext_vector_type(8)));

#if defined(__has_builtin)
#if __has_builtin(__builtin_amdgcn_fdot2)
#define HAVE_FDOT2 1
#endif
#if __has_builtin(__builtin_amdgcn_exp2f)
#define FEXP2(x) __builtin_amdgcn_exp2f(x)
#endif
#endif
#ifndef FEXP2
#define FEXP2(x) exp2f(x)
#endif

__device__ __forceinline__ f32x8 cvt8(f16x8 v) {
    return __builtin_convertvector(v, f32x8);
}

// DPP butterfly add step — pure VALU, no LDS pipe (vs __shfl_xor's ds_bpermute).
// CTRL: 0xB1 = quad_perm(1,0,3,2) (xor1), 0x4E = quad_perm(2,3,0,1) (xor2),
// 0x141 = row_half_mirror (xor4 once quads uniform), 0x140 = row_mirror (xor8
// once 8-groups uniform). CTRL must be a compile-time constant -> template.
template <int CTRL>
__device__ __forceinline__ float dpp_add(float v) {
    int o = __builtin_amdgcn_update_dpp(0, __builtin_bit_cast(int, v),
                                        CTRL, 0xF, 0xF, true);
    return v + __builtin_bit_cast(float, o);
}

// ---------------------------------------------------------------------------
// K1: merged prep + bucketing.
//   blocks [0, B0)        : chunk bucketing with LDS counting-sort so the
//                           staging flush is coalesced per-bucket runs
//   blocks [B0, B0+256)   : W transpose -> fp16
//   blocks [B0+256, ...)  : x fp32 -> fp16 hi/lo split
// gcursor must be zeroed before launch (hipMemsetAsync); reservation adds
// the bk*BCAP base so no cross-block init ordering is needed.
// ---------------------------------------------------------------------------
__global__ __launch_bounds__(256) void k1_prep_bucket_kernel(
    const float* __restrict__ W0, const float* __restrict__ W1,
    const float* __restrict__ W2, const float* __restrict__ W3,
    _Float16* __restrict__ wt,
    const float* __restrict__ x, _Float16* __restrict__ xh,
    _Float16* __restrict__ xlo, int total,
    const int* __restrict__ ei, int* __restrict__ gcursor,
    int2* __restrict__ staging, int E, int B0)
{
    __shared__ int2 pairs[CHUNK];          // 32 KB
    __shared__ int bh[256], bbase[256], exb[256], scn[256];
    int t = threadIdx.x;
    int bid = blockIdx.x;

    if (bid < B0) {
        // ---- bucket one chunk of edges ----
        bh[t] = 0;
        __syncthreads();
        int base = bid * CHUNK;
        int srcv[16], dstv[16], rb[16];
#pragma unroll
        for (int j = 0; j < 16; j++) {
            int e = base + t + j * 256;
            if (e < E) {
                int d = ei[E + e];
                srcv[j] = ei[e];
                dstv[j] = d;
                int bk = d >> 8;
                int r = atomicAdd(&bh[bk], 1);
                rb[j] = (r << 8) | bk;
            } else rb[j] = -1;
        }
        __syncthreads();
        // inclusive scan of bh into scn
        int v = bh[t];
        scn[t] = v;
        __syncthreads();
        for (int off = 1; off < 256; off <<= 1) {
            int u = (t >= off) ? scn[t - off] : 0;
            __syncthreads();
            scn[t] += u;
            __syncthreads();
        }
        int ex = scn[t] - v;
        int tot = scn[255];
        exb[t] = ex;
        if (v) bbase[t] = t * BCAP + atomicAdd(&gcursor[t], v);
        __syncthreads();
        // scatter pairs into LDS, bucket-sorted within the chunk
#pragma unroll
        for (int j = 0; j < 16; j++) {
            if (rb[j] >= 0) {
                int bk = rb[j] & 255, r = rb[j] >> 8;
                pairs[exb[bk] + r] = make_int2(srcv[j], dstv[j]);
            }
        }
        __syncthreads();
        // coalesced flush: consecutive i -> same-bucket runs (avg ~16 pairs)
        for (int i = t; i < tot; i += 256) {
            int2 p = pairs[i];
            int bk = p.y >> 8;
            staging[bbase[bk] + (i - exb[bk])] = p;
        }
    } else if (bid < B0 + 256) {
        // ---- W transpose -> fp16 ----
        int idx = (bid - B0) * 256 + t;     // 4*128*128
        int m = idx >> 14;
        int k = (idx >> 7) & 127;
        int n = idx & 127;
        const float* W = (m == 0) ? W0 : (m == 1) ? W1 : (m == 2) ? W2 : W3;
        wt[m * 16384 + n * 128 + k] = (_Float16)W[k * 128 + n];
    } else {
        // ---- x -> fp16 hi/lo split ----
        int i = (bid - B0 - 256) * 256 + t;
        if (i * 2 < total) {
            float2 f = *(const float2*)(x + (size_t)i * 2);
            _Float16 h0 = (_Float16)f.x, h1 = (_Float16)f.y;
            _Float16 l0 = (_Float16)(f.x - (float)h0), l1 = (_Float16)(f.y - (float)h1);
            *(f16x2*)(xh  + (size_t)i * 2) = (f16x2){h0, h1};
            *(f16x2*)(xlo + (size_t)i * 2) = (f16x2){l0, l1};
        }
    }
}

// ---------------------------------------------------------------------------
// fp16 MFMA GEMM block body, LDS-staged W (34 KB). C = Ah@W + Al@W, fp32 acc.
// ---------------------------------------------------------------------------
__device__ __forceinline__ void gemm_body(
    const _Float16* __restrict__ Ahi, const _Float16* __restrict__ Alo,
    const _Float16* __restrict__ Wt, _Float16* __restrict__ C, int N,
    int bx, _Float16* ldsW)
{
    const int tid = threadIdx.x;
    const int wave = tid >> 6;
    const int lane = tid & 63;
    const int mrow = lane & 15;
    const int quad = lane >> 4;
    const int rbase = bx * 128 + wave * 32;

    // staging loads first (latency overlaps A loads)
    const int sn = tid >> 1, shf = tid & 1;
    float4 stg[8];
    {
        const float4* g = (const float4*)(Wt + sn * 128 + shf * 64);
#pragma unroll
        for (int j = 0; j < 8; j++) stg[j] = g[j];
    }

    f16x8 ah[2][4], al[2][4];
#pragma unroll
    for (int rt = 0; rt < 2; rt++) {
        int r = rbase + rt * 16 + mrow;
        if (r > N - 1) r = N - 1;
        const _Float16* pa = Ahi + (size_t)r * 128 + quad * 8;
        const _Float16* pl = Alo + (size_t)r * 128 + quad * 8;
#pragma unroll
        for (int s = 0; s < 4; s++) {
            ah[rt][s] = *(const f16x8*)(pa + s * 32);
            al[rt][s] = *(const f16x8*)(pl + s * 32);
        }
    }

    {
        float4* d = (float4*)&ldsW[sn * 136 + shf * 64];
#pragma unroll
        for (int j = 0; j < 8; j++) d[j] = stg[j];
    }

    f32x4 acc[2][8];
#pragma unroll
    for (int rt = 0; rt < 2; rt++)
#pragma unroll
        for (int c = 0; c < 8; c++) acc[rt][c] = (f32x4){0.f, 0.f, 0.f, 0.f};

    __syncthreads();

#pragma unroll
    for (int s = 0; s < 4; s++) {
#pragma unroll
        for (int c = 0; c < 8; c++) {
            f16x8 bw = *(const f16x8*)&ldsW[(c * 16 + mrow) * 136 + s * 32 + quad * 8];
            acc[0][c] = __builtin_amdgcn_mfma_f32_16x16x32_f16(ah[0][s], bw, acc[0][c], 0, 0, 0);
            acc[0][c] = __builtin_amdgcn_mfma_f32_16x16x32_f16(al[0][s], bw, acc[0][c], 0, 0, 0);
            acc[1][c] = __builtin_amdgcn_mfma_f32_16x16x32_f16(ah[1][s], bw, acc[1][c], 0, 0, 0);
            acc[1][c] = __builtin_amdgcn_mfma_f32_16x16x32_f16(al[1][s], bw, acc[1][c], 0, 0, 0);
        }
    }

    // D mapping: col = lane&15, row = quad*4 + reg
#pragma unroll
    for (int rt = 0; rt < 2; rt++)
#pragma unroll
        for (int i = 0; i < 4; i++) {
            int r = rbase + rt * 16 + quad * 4 + i;
            if (r < N) {
                _Float16* cr = C + (size_t)r * 128 + mrow;
#pragma unroll
                for (int c = 0; c < 8; c++) cr[c * 16] = (_Float16)acc[rt][c][i];
            }
        }
}

// standalone two-dispatch-style GEMM (layer 2): blockIdx.y selects W/output
__global__ __launch_bounds__(256) void gemm_f16_kernel(
    const _Float16* __restrict__ Ahi, const _Float16* __restrict__ Alo,
    const _Float16* __restrict__ Wt0, const _Float16* __restrict__ Wt1,
    _Float16* __restrict__ Cl, _Float16* __restrict__ Cr, int N)
{
    __shared__ _Float16 ldsW[128 * 136];
    gemm_body(Ahi, Alo, blockIdx.y ? Wt1 : Wt0, blockIdx.y ? Cr : Cl, N,
              blockIdx.x, ldsW);
}

// ---------------------------------------------------------------------------
// K2: merged per-bucket counting sort (passB) + layer-1 GEMM (both halves).
//   blocks [0, NB)                 : counting sort -> start/deg/sorted_src
//   blocks [NB, NB+gx)             : gemm y=0 (Cl)
//   blocks [NB+gx, NB+2*gx)        : gemm y=1 (Cr)
// sorted_src stores src<<8 = row BYTE offset (saves shifts in the fused
// gather; garbage in bucket padding is clamped there with one umin).
// ---------------------------------------------------------------------------
__global__ __launch_bounds__(256) void k2_sort_gemm_kernel(
    const int2* __restrict__ staging, const int* __restrict__ gcursor,
    int* __restrict__ start, int* __restrict__ deg,
    int* __restrict__ sorted_src, int N, int NBv,
    const _Float16* __restrict__ Ahi, const _Float16* __restrict__ Alo,
    const _Float16* __restrict__ Wt0, const _Float16* __restrict__ Wt1,
    _Float16* __restrict__ Cl, _Float16* __restrict__ Cr, int gx)
{
    __shared__ _Float16 ldsW[128 * 136];
    int bx = blockIdx.x;
    if (bx < NBv) {
        int* lhist = (int*)ldsW;
        int* lscan = lhist + 256;
        int* lcur  = lhist + 512;
        int b = bx, t = threadIdx.x;
        int r0 = b * BCAP;
        int r1 = r0 + gcursor[b];     // final fill for this bucket
        lhist[t] = 0;
        __syncthreads();
        for (int i = r0 + t; i < r1; i += 256) atomicAdd(&lhist[staging[i].y & 255], 1);
        __syncthreads();
        int v = lhist[t];
        lscan[t] = v;
        __syncthreads();
        for (int off = 1; off < 256; off <<= 1) {
            int u = (t >= off) ? lscan[t - off] : 0;
            __syncthreads();
            lscan[t] += u;
            __syncthreads();
        }
        int excl = lscan[t] - v;
        int node = b * NPB + t;
        if (node < N) { start[node] = r0 + excl; deg[node] = v; }
        lcur[t] = excl;
        __syncthreads();
        for (int i = r0 + t; i < r1; i += 256) {
            int2 p = staging[i];
            int rank = atomicAdd(&lcur[p.y & 255], 1);
            sorted_src[r0 + rank] = p.x << 8;   // pre-scaled byte offset
        }
    } else {
        int gb = bx - NBv;
        int y = (gb >= gx) ? 1 : 0;
        int gxi = y ? gb - gx : gb;
        gemm_body(Ahi, Alo, y ? Wt1 : Wt0, y ? Cr : Cl, N, gxi, ldsW);
    }
}

// ---------------------------------------------------------------------------
// Fused score+softmax+aggregate.
// TWO nodes per wave, lockstep over max(K0,K1) groups with per-node masking;
// 2-stage software pipeline (8 gathers in flight during compute).
// Instruction diet vs r5: (1) sorted_src holds pre-scaled byte offsets ->
// gather addr = uniform base + 32-bit voffset; (2) group 0 specialized so
// the self-loop cndmask leaves the loop; (3) tail/garbage slots handled by a
// single v_min_u32 clamp (their e is zeroed by the iv<M mask anyway);
// (4) exp2 via __builtin_amdgcn_exp2f (1 trans op, no libm fixup).
// 16 lanes/edge (f16x8/lane), 4 edge slots/group. DPP reduction; H==2 stops
// at the 8-lane boundary (lanes 0-7 head 0, 8-15 head 1). att pre-scaled by
// log2(e). Self-loop = virtual edge 0. Lanes 0-15 store node0, 16-31 node1.
// ---------------------------------------------------------------------------
template <int H, bool BFOUT>
__global__ __launch_bounds__(256) void gat_fused_kernel(
    const _Float16* __restrict__ xl, const _Float16* __restrict__ xr,
    const float* __restrict__ att, const float* __restrict__ bias,
    const int* __restrict__ start, const int* __restrict__ deg,
    const int* __restrict__ sorted_src,
    float* __restrict__ outf, _Float16* __restrict__ oh,
    _Float16* __restrict__ ol, int N)
{
    const int wid = threadIdx.x >> 6;
    const int n0 = blockIdx.x * 8 + wid * 2;
    if (n0 >= N) return;
    const bool has1 = (n0 + 1) < N;
    const int n1 = has1 ? n0 + 1 : n0;
    const int lane = threadIdx.x & 63;
    const int g  = lane >> 4;          // edge slot 0..3 within a group
    const int hl = lane & 15;          // feature slot: ch [hl*8, hl*8+8)
    const unsigned hl16 = (unsigned)hl * 16;
    const _Float16 NS = (_Float16)NEG_SLOPE;
    const float L2E = 1.44269504f;

    const f16x8 b40 = *(const f16x8*)(xr + (size_t)n0 * 128 + hl * 8);
    const f16x8 b41 = *(const f16x8*)(xr + (size_t)n1 * 128 + hl * 8);
    float4 at0 = *(const float4*)(att + hl * 8);
    float4 at1 = *(const float4*)(att + hl * 8 + 4);
#if defined(HAVE_FDOT2)
    f16x2 av0 = {(_Float16)(at0.x * L2E), (_Float16)(at0.y * L2E)};
    f16x2 av1 = {(_Float16)(at0.z * L2E), (_Float16)(at0.w * L2E)};
    f16x2 av2 = {(_Float16)(at1.x * L2E), (_Float16)(at1.y * L2E)};
    f16x2 av3 = {(_Float16)(at1.z * L2E), (_Float16)(at1.w * L2E)};
#else
    f32x8 avf = {at0.x * L2E, at0.y * L2E, at0.z * L2E, at0.w * L2E,
                 at1.x * L2E, at1.y * L2E, at1.z * L2E, at1.w * L2E};
#endif

    auto score = [&](f16x8 a_, f16x8 b4_) -> float {
        f16x8 t = a_ + b4_;
        f16x8 u = __builtin_elementwise_max(t, t * NS);
#if defined(HAVE_FDOT2)
        f16x2 u0 = __builtin_shufflevector(u, u, 0, 1);
        f16x2 u1 = __builtin_shufflevector(u, u, 2, 3);
        f16x2 u2 = __builtin_shufflevector(u, u, 4, 5);
        f16x2 u3 = __builtin_shufflevector(u, u, 6, 7);
        return __builtin_amdgcn_fdot2(u0, av0,
               __builtin_amdgcn_fdot2(u1, av1,
               __builtin_amdgcn_fdot2(u2, av2,
               __builtin_amdgcn_fdot2(u3, av3, 0.f, false), false), false), false);
#else
        f32x8 uf = cvt8(u);
        float p = 0.f;
#pragma unroll
        for (int i = 0; i < 8; i++) p += uf[i] * avf[i];
        return p;
#endif
    };

    // 16-lane (or 8-lane for H==2) butterfly reduce, pure DPP.
    auto red = [&](float p) -> float {
        p = dpp_add<0xB1>(p);            // xor1
        p = dpp_add<0x4E>(p);            // xor2
        p = dpp_add<0x141>(p);           // xor4 (row_half_mirror)
        if (H == 1) p = dpp_add<0x140>(p);   // xor8 (row_mirror)
        return p;
    };

    const int s00 = start[n0];
    const int M0  = deg[n0] + 1;       // incl. self-loop at iv==0
    const int s01 = start[n1];
    const int M1  = deg[n1] + 1;
    const int Mmax = (M0 > M1) ? M0 : M1;
    const int K   = (Mmax + 3) >> 2;   // lockstep group count
    const int KK  = (K + 1) & ~1;      // rounded up to pipeline pairs (>=2)

    const unsigned cap = (unsigned)(N - 1) << 8;
    // clamped pre-scaled offset load: garbage in padding -> last row (e=0)
    auto ldoff = [&](int pos) -> unsigned {
        unsigned v = (unsigned)sorted_src[pos];
        return (v < cap) ? v : cap;
    };
    auto grow = [&](unsigned off) -> f16x8 {
        return *(const f16x8*)((const char*)xl + (size_t)(off + hl16));
    };

    f32x8 acc0 = {0.f, 0.f, 0.f, 0.f, 0.f, 0.f, 0.f, 0.f};
    f32x8 acc1 = {0.f, 0.f, 0.f, 0.f, 0.f, 0.f, 0.f, 0.f};
    float den0 = 0.f, den1 = 0.f;

    auto cone = [&](int kk, f16x8 a, f16x8 b4_, int M_, float& den_, f32x8& acc_) {
        float p = red(score(a, b4_));
        float e = (4 * kk + g < M_) ? FEXP2(p) : 0.f;
        den_ += e;
#pragma unroll
        for (int i = 0; i < 8; i++)
            acc_[i] = fmaf((float)a[i], e, acc_[i]);   // v_fma_mix
    };

    // 2-stage pipeline; group 0 specialized (self-loop in slot g==0)
    unsigned o00 = (g == 0) ? (unsigned)n0 << 8 : ldoff(s00 + g - 1);
    unsigned o01 = (g == 0) ? (unsigned)n1 << 8 : ldoff(s01 + g - 1);
    unsigned o10 = ldoff(s00 + g + 3);
    unsigned o11 = ldoff(s01 + g + 3);
    f16x8 c00 = grow(o00), c01 = grow(o01), c10 = grow(o10), c11 = grow(o11);
    for (int k = 2; k < KK; k += 2) {
        unsigned p00 = ldoff(s00 + 4 * k + g - 1);
        unsigned p01 = ldoff(s01 + 4 * k + g - 1);
        unsigned p10 = ldoff(s00 + 4 * k + g + 3);
        unsigned p11 = ldoff(s01 + 4 * k + g + 3);
        f16x8 d00 = grow(p00), d01 = grow(p01), d10 = grow(p10), d11 = grow(p11);
        cone(k - 2, c00, b40, M0, den0, acc0);
        cone(k - 2, c01, b41, M1, den1, acc1);
        cone(k - 1, c10, b40, M0, den0, acc0);
        cone(k - 1, c11, b41, M1, den1, acc1);
        c00 = d00; c01 = d01; c10 = d10; c11 = d11;
    }
    cone(KK - 2, c00, b40, M0, den0, acc0);
    cone(KK - 2, c01, b41, M1, den1, acc1);
    cone(KK - 1, c10, b40, M0, den0, acc0);
    cone(KK - 1, c11, b41, M1, den1, acc1);

    // combine the 4 edge-groups (feature-aligned): masks 16 and 32 only.
    den0 += __shfl_xor(den0, 16, 64);
    den0 += __shfl_xor(den0, 32, 64);
    den1 += __shfl_xor(den1, 16, 64);
    den1 += __shfl_xor(den1, 32, 64);
#pragma unroll
    for (int i = 0; i < 8; i++) {
        acc0[i] += __shfl_xor(acc0[i], 16, 64);
        acc0[i] += __shfl_xor(acc0[i], 32, 64);
        acc1[i] += __shfl_xor(acc1[i], 16, 64);
        acc1[i] += __shfl_xor(acc1[i], 32, 64);
    }

    // lanes 0-15 store node0, lanes 16-31 store node1 (parallel epilogue)
    const int which = lane >> 4;
    if (which == 0 || (which == 1 && has1)) {
        float inv = 1.0f / (which == 0 ? den0 : den1);
        int nodeo = (which == 0) ? n0 : n1;
        float4 bi0 = *(const float4*)(bias + hl * 8);
        float4 bi1 = *(const float4*)(bias + hl * 8 + 4);
        float o[8];
#pragma unroll
        for (int i = 0; i < 8; i++) {
            float a = (which == 0) ? acc0[i] : acc1[i];
            float b = (i < 4) ? ((i == 0) ? bi0.x : (i == 1) ? bi0.y : (i == 2) ? bi0.z : bi0.w)
                              : ((i == 4) ? bi1.x : (i == 5) ? bi1.y : (i == 6) ? bi1.z : bi1.w);
            o[i] = a * inv + b;
        }
        if (BFOUT) {   // next layer's A: fp16 hi+lo split
            f16x8 hv, lv;
#pragma unroll
            for (int i = 0; i < 8; i++) {
                _Float16 h = (_Float16)o[i];
                hv[i] = h;
                lv[i] = (_Float16)(o[i] - (float)h);
            }
            *(f16x8*)(oh + (size_t)nodeo * 128 + hl * 8) = hv;
            *(f16x8*)(ol + (size_t)nodeo * 128 + hl * 8) = lv;
        } else {
            *(float4*)(outf + (size_t)nodeo * 128 + hl * 8) =
                make_float4(o[0], o[1], o[2], o[3]);
            *(float4*)(outf + (size_t)nodeo * 128 + hl * 8 + 4) =
                make_float4(o[4], o[5], o[6], o[7]);
        }
    }
}

// ---------------------------------------------------------------------------
extern "C" void kernel_launch(void* const* d_in, const int* in_sizes, int n_in,
                              void* d_out, int out_size, void* d_ws, size_t ws_size,
                              hipStream_t stream)
{
    const float* x    = (const float*)d_in[0];
    const int*   ei   = (const int*)d_in[1];
    const float* Wl1  = (const float*)d_in[3];
    const float* Wr1  = (const float*)d_in[4];
    const float* att1 = (const float*)d_in[5];
    const float* b1   = (const float*)d_in[6];
    const float* Wl2  = (const float*)d_in[7];
    const float* Wr2  = (const float*)d_in[8];
    const float* att2 = (const float*)d_in[9];
    const float* b2   = (const float*)d_in[10];
    float* out = (float*)d_out;

    const int N  = in_sizes[0] / 128;
    const int E  = in_sizes[1] / 2;
    const int NB = (N + NPB - 1) / NPB;

    const size_t nf = (size_t)N * 128;
    _Float16* xlf  = (_Float16*)d_ws;                 // nf fp16 (gather array)
    _Float16* xrf  = xlf + nf;                        // nf fp16
    _Float16* ah   = xrf + nf;                        // nf fp16 (A hi: x, then h)
    _Float16* al   = ah + nf;                         // nf fp16 (A lo)
    _Float16* wt   = al + nf;                         // 4*16384 fp16
    int* gcursor   = (int*)(wt + 4 * 16384);          // 256
    int* start     = gcursor + 256;                   // N
    int* deg       = start + N;                       // N
    size_t stgoff  = ((size_t)(deg + N) + 7) & ~(size_t)7;
    int2* staging  = (int2*)stgoff;                   // NB*BCAP int2 (padded)
    int* sorted_src = (int*)(staging + (size_t)NB * BCAP);  // NB*BCAP + 64 ints

    const int grid_chunk = (E + CHUNK - 1) / CHUNK;
    const int node_grid  = (N + 7) / 8;               // 8 nodes per block (2/wave)
    const int gemm_gx    = (N + 127) / 128;
    const int split_grid = (int)((nf / 2 + 255) / 256);

    // ---- zero bucket cursors (captured async op) ----
    hipMemsetAsync(gcursor, 0, 256 * sizeof(int), stream);

    // ---- K1: prep (W fp16-transpose, x hi/lo split) + chunk bucketing ----
    k1_prep_bucket_kernel<<<grid_chunk + 256 + split_grid, 256, 0, stream>>>(
        Wl1, Wr1, Wl2, Wr2, wt, x, ah, al, (int)nf,
        ei, gcursor, staging, E, grid_chunk);

    // ---- K2: per-bucket counting sort + layer-1 GEMM (both halves) ----
    k2_sort_gemm_kernel<<<NB + 2 * gemm_gx, 256, 0, stream>>>(
        staging, gcursor, start, deg, sorted_src, N, NB,
        ah, al, wt + 0 * 16384, wt + 1 * 16384, xlf, xrf, gemm_gx);

    // ---- Layer 1 fused ----
    gat_fused_kernel<2, true><<<node_grid, 256, 0, stream>>>(
        xlf, xrf, att1, b1, start, deg, sorted_src, nullptr, ah, al, N);

    // ---- Layer 2: GEMM + fused ----
    gemm_f16_kernel<<<dim3(gemm_gx, 2), 256, 0, stream>>>(
        ah, al, wt + 2 * 16384, wt + 3 * 16384, xlf, xrf, N);
    gat_fused_kernel<1, false><<<node_grid, 256, 0, stream>>>(
        xlf, xrf, att2, b2, start, deg, sorted_src, out, nullptr, nullptr, N);
}

// Round 8
// 265.640 us; speedup vs baseline: 1.0075x; 1.0075x over previous
//
#include <hip/hip_runtime.h>

#define NEG_SLOPE 0.2f
#define NPB 256          // nodes per dst-bucket (bucket = dst >> 8)
#define CHUNK 4096       // edges per partition block
#define BCAP 5120        // padded bucket capacity (expected fill 4096, +16 sigma)

typedef _Float16 f16x8 __attribute__((ext_vector_type(8)));
typedef _Float16 f16x4 __attribute__((ext_vector_type(4)));
typedef _Float16 f16x2 __attribute__((ext_vector_type(2)));
typedef float    f32x4 __attribute__((ext_vector_type(4)));
typedef float    f32x8 __attribute__((ext_vector_type(8)));

#if defined(__has_builtin)
#if __has_builtin(__builtin_amdgcn_fdot2)
#define HAVE_FDOT2 1
#endif
#if __has_builtin(__builtin_amdgcn_exp2f)
#define FEXP2(x) __builtin_amdgcn_exp2f(x)
#endif
#endif
#ifndef FEXP2
#define FEXP2(x) exp2f(x)
#endif

__device__ __forceinline__ f32x8 cvt8(f16x8 v) {
    return __builtin_convertvector(v, f32x8);
}

// DPP butterfly add step — pure VALU, no LDS pipe (vs __shfl_xor's ds_bpermute).
// CTRL: 0xB1 = quad_perm(1,0,3,2) (xor1), 0x4E = quad_perm(2,3,0,1) (xor2),
// 0x141 = row_half_mirror (xor4 once quads uniform), 0x140 = row_mirror (xor8
// once 8-groups uniform). CTRL must be a compile-time constant -> template.
template <int CTRL>
__device__ __forceinline__ float dpp_add(float v) {
    int o = __builtin_amdgcn_update_dpp(0, __builtin_bit_cast(int, v),
                                        CTRL, 0xF, 0xF, true);
    return v + __builtin_bit_cast(float, o);
}

// ---------------------------------------------------------------------------
// K1: merged prep + bucketing.
//   blocks [0, B0)        : chunk bucketing with LDS counting-sort so the
//                           staging flush is coalesced per-bucket runs
//   blocks [B0, B0+256)   : W transpose -> fp16
//   blocks [B0+256, ...)  : x fp32 -> fp16 hi/lo split
// gcursor must be zeroed before launch (hipMemsetAsync); reservation adds
// the bk*BCAP base so no cross-block init ordering is needed.
// ---------------------------------------------------------------------------
__global__ __launch_bounds__(256) void k1_prep_bucket_kernel(
    const float* __restrict__ W0, const float* __restrict__ W1,
    const float* __restrict__ W2, const float* __restrict__ W3,
    _Float16* __restrict__ wt,
    const float* __restrict__ x, _Float16* __restrict__ xh,
    _Float16* __restrict__ xlo, int total,
    const int* __restrict__ ei, int* __restrict__ gcursor,
    int2* __restrict__ staging, int E, int B0)
{
    __shared__ int2 pairs[CHUNK];          // 32 KB
    __shared__ int bh[256], bbase[256], exb[256], scn[256];
    int t = threadIdx.x;
    int bid = blockIdx.x;

    if (bid < B0) {
        // ---- bucket one chunk of edges ----
        bh[t] = 0;
        __syncthreads();
        int base = bid * CHUNK;
        int srcv[16], dstv[16], rb[16];
#pragma unroll
        for (int j = 0; j < 16; j++) {
            int e = base + t + j * 256;
            if (e < E) {
                int d = ei[E + e];
                srcv[j] = ei[e];
                dstv[j] = d;
                int bk = d >> 8;
                int r = atomicAdd(&bh[bk], 1);
                rb[j] = (r << 8) | bk;
            } else rb[j] = -1;
        }
        __syncthreads();
        // inclusive scan of bh into scn
        int v = bh[t];
        scn[t] = v;
        __syncthreads();
        for (int off = 1; off < 256; off <<= 1) {
            int u = (t >= off) ? scn[t - off] : 0;
            __syncthreads();
            scn[t] += u;
            __syncthreads();
        }
        int ex = scn[t] - v;
        int tot = scn[255];
        exb[t] = ex;
        if (v) bbase[t] = t * BCAP + atomicAdd(&gcursor[t], v);
        __syncthreads();
        // scatter pairs into LDS, bucket-sorted within the chunk
#pragma unroll
        for (int j = 0; j < 16; j++) {
            if (rb[j] >= 0) {
                int bk = rb[j] & 255, r = rb[j] >> 8;
                pairs[exb[bk] + r] = make_int2(srcv[j], dstv[j]);
            }
        }
        __syncthreads();
        // coalesced flush: consecutive i -> same-bucket runs (avg ~16 pairs)
        for (int i = t; i < tot; i += 256) {
            int2 p = pairs[i];
            int bk = p.y >> 8;
            staging[bbase[bk] + (i - exb[bk])] = p;
        }
    } else if (bid < B0 + 256) {
        // ---- W transpose -> fp16 ----
        int idx = (bid - B0) * 256 + t;     // 4*128*128
        int m = idx >> 14;
        int k = (idx >> 7) & 127;
        int n = idx & 127;
        const float* W = (m == 0) ? W0 : (m == 1) ? W1 : (m == 2) ? W2 : W3;
        wt[m * 16384 + n * 128 + k] = (_Float16)W[k * 128 + n];
    } else {
        // ---- x -> fp16 hi/lo split ----
        int i = (bid - B0 - 256) * 256 + t;
        if (i * 2 < total) {
            float2 f = *(const float2*)(x + (size_t)i * 2);
            _Float16 h0 = (_Float16)f.x, h1 = (_Float16)f.y;
            _Float16 l0 = (_Float16)(f.x - (float)h0), l1 = (_Float16)(f.y - (float)h1);
            *(f16x2*)(xh  + (size_t)i * 2) = (f16x2){h0, h1};
            *(f16x2*)(xlo + (size_t)i * 2) = (f16x2){l0, l1};
        }
    }
}

// ---------------------------------------------------------------------------
// fp16 MFMA GEMM block body, LDS-staged W (34 KB). C = Ah@W + Al@W, fp32 acc.
// ---------------------------------------------------------------------------
__device__ __forceinline__ void gemm_body(
    const _Float16* __restrict__ Ahi, const _Float16* __restrict__ Alo,
    const _Float16* __restrict__ Wt, _Float16* __restrict__ C, int N,
    int bx, _Float16* ldsW)
{
    const int tid = threadIdx.x;
    const int wave = tid >> 6;
    const int lane = tid & 63;
    const int mrow = lane & 15;
    const int quad = lane >> 4;
    const int rbase = bx * 128 + wave * 32;

    // staging loads first (latency overlaps A loads)
    const int sn = tid >> 1, shf = tid & 1;
    float4 stg[8];
    {
        const float4* g = (const float4*)(Wt + sn * 128 + shf * 64);
#pragma unroll
        for (int j = 0; j < 8; j++) stg[j] = g[j];
    }

    f16x8 ah[2][4], al[2][4];
#pragma unroll
    for (int rt = 0; rt < 2; rt++) {
        int r = rbase + rt * 16 + mrow;
        if (r > N - 1) r = N - 1;
        const _Float16* pa = Ahi + (size_t)r * 128 + quad * 8;
        const _Float16* pl = Alo + (size_t)r * 128 + quad * 8;
#pragma unroll
        for (int s = 0; s < 4; s++) {
            ah[rt][s] = *(const f16x8*)(pa + s * 32);
            al[rt][s] = *(const f16x8*)(pl + s * 32);
        }
    }

    {
        float4* d = (float4*)&ldsW[sn * 136 + shf * 64];
#pragma unroll
        for (int j = 0; j < 8; j++) d[j] = stg[j];
    }

    f32x4 acc[2][8];
#pragma unroll
    for (int rt = 0; rt < 2; rt++)
#pragma unroll
        for (int c = 0; c < 8; c++) acc[rt][c] = (f32x4){0.f, 0.f, 0.f, 0.f};

    __syncthreads();

#pragma unroll
    for (int s = 0; s < 4; s++) {
#pragma unroll
        for (int c = 0; c < 8; c++) {
            f16x8 bw = *(const f16x8*)&ldsW[(c * 16 + mrow) * 136 + s * 32 + quad * 8];
            acc[0][c] = __builtin_amdgcn_mfma_f32_16x16x32_f16(ah[0][s], bw, acc[0][c], 0, 0, 0);
            acc[0][c] = __builtin_amdgcn_mfma_f32_16x16x32_f16(al[0][s], bw, acc[0][c], 0, 0, 0);
            acc[1][c] = __builtin_amdgcn_mfma_f32_16x16x32_f16(ah[1][s], bw, acc[1][c], 0, 0, 0);
            acc[1][c] = __builtin_amdgcn_mfma_f32_16x16x32_f16(al[1][s], bw, acc[1][c], 0, 0, 0);
        }
    }

    // D mapping: col = lane&15, row = quad*4 + reg
#pragma unroll
    for (int rt = 0; rt < 2; rt++)
#pragma unroll
        for (int i = 0; i < 4; i++) {
            int r = rbase + rt * 16 + quad * 4 + i;
            if (r < N) {
                _Float16* cr = C + (size_t)r * 128 + mrow;
#pragma unroll
                for (int c = 0; c < 8; c++) cr[c * 16] = (_Float16)acc[rt][c][i];
            }
        }
}

// standalone two-dispatch-style GEMM (layer 2): blockIdx.y selects W/output
__global__ __launch_bounds__(256) void gemm_f16_kernel(
    const _Float16* __restrict__ Ahi, const _Float16* __restrict__ Alo,
    const _Float16* __restrict__ Wt0, const _Float16* __restrict__ Wt1,
    _Float16* __restrict__ Cl, _Float16* __restrict__ Cr, int N)
{
    __shared__ _Float16 ldsW[128 * 136];
    gemm_body(Ahi, Alo, blockIdx.y ? Wt1 : Wt0, blockIdx.y ? Cr : Cl, N,
              blockIdx.x, ldsW);
}

// ---------------------------------------------------------------------------
// K2: merged per-bucket counting sort (passB) + layer-1 GEMM (both halves).
//   blocks [0, NB)                 : counting sort -> start/deg/sorted_src
//   blocks [NB, NB+gx)             : gemm y=0 (Cl)
//   blocks [NB+gx, NB+2*gx)        : gemm y=1 (Cr)
// sorted_src stores src<<8 = row BYTE offset (saves shifts in the fused
// gather; garbage in bucket padding is clamped there with one umin).
// ---------------------------------------------------------------------------
__global__ __launch_bounds__(256) void k2_sort_gemm_kernel(
    const int2* __restrict__ staging, const int* __restrict__ gcursor,
    int* __restrict__ start, int* __restrict__ deg,
    int* __restrict__ sorted_src, int N, int NBv,
    const _Float16* __restrict__ Ahi, const _Float16* __restrict__ Alo,
    const _Float16* __restrict__ Wt0, const _Float16* __restrict__ Wt1,
    _Float16* __restrict__ Cl, _Float16* __restrict__ Cr, int gx)
{
    __shared__ _Float16 ldsW[128 * 136];
    int bx = blockIdx.x;
    if (bx < NBv) {
        int* lhist = (int*)ldsW;
        int* lscan = lhist + 256;
        int* lcur  = lhist + 512;
        int b = bx, t = threadIdx.x;
        int r0 = b * BCAP;
        int r1 = r0 + gcursor[b];     // final fill for this bucket
        lhist[t] = 0;
        __syncthreads();
        for (int i = r0 + t; i < r1; i += 256) atomicAdd(&lhist[staging[i].y & 255], 1);
        __syncthreads();
        int v = lhist[t];
        lscan[t] = v;
        __syncthreads();
        for (int off = 1; off < 256; off <<= 1) {
            int u = (t >= off) ? lscan[t - off] : 0;
            __syncthreads();
            lscan[t] += u;
            __syncthreads();
        }
        int excl = lscan[t] - v;
        int node = b * NPB + t;
        if (node < N) { start[node] = r0 + excl; deg[node] = v; }
        lcur[t] = excl;
        __syncthreads();
        for (int i = r0 + t; i < r1; i += 256) {
            int2 p = staging[i];
            int rank = atomicAdd(&lcur[p.y & 255], 1);
            sorted_src[r0 + rank] = p.x << 8;   // pre-scaled byte offset
        }
    } else {
        int gb = bx - NBv;
        int y = (gb >= gx) ? 1 : 0;
        int gxi = y ? gb - gx : gb;
        gemm_body(Ahi, Alo, y ? Wt1 : Wt0, y ? Cr : Cl, N, gxi, ldsW);
    }
}

// ---------------------------------------------------------------------------
// Fused score+softmax+aggregate.
// PERSISTENT grid-stride over node pairs (2048 blocks; each wave handles
// ~3 pairs serially), with next-pair start/deg PREFETCH issued before the
// current pair's inner loop — removes one memory round-trip from every
// pair's serial startup chain (the round-7 latency diagnosis). Inner loop
// unchanged from round 7: 2 nodes/wave lockstep, 2-stage pipeline, byte-
// offset gathers, group-0 self-loop specialization, v_exp2 softmax, DPP
// reduction. Lanes 0-15 store node0, 16-31 node1.
// ---------------------------------------------------------------------------
template <int H, bool BFOUT>
__global__ __launch_bounds__(256) void gat_fused_kernel(
    const _Float16* __restrict__ xl, const _Float16* __restrict__ xr,
    const float* __restrict__ att, const float* __restrict__ bias,
    const int* __restrict__ start, const int* __restrict__ deg,
    const int* __restrict__ sorted_src,
    float* __restrict__ outf, _Float16* __restrict__ oh,
    _Float16* __restrict__ ol, int N, int npairs)
{
    const int wid = threadIdx.x >> 6;
    int p = blockIdx.x * 4 + wid;
    if (p >= npairs) return;
    const int stride = gridDim.x * 4;
    const int lane = threadIdx.x & 63;
    const int g  = lane >> 4;          // edge slot 0..3 within a group
    const int hl = lane & 15;          // feature slot: ch [hl*8, hl*8+8)
    const unsigned hl16 = (unsigned)hl * 16;
    const _Float16 NS = (_Float16)NEG_SLOPE;
    const float L2E = 1.44269504f;

    float4 at0 = *(const float4*)(att + hl * 8);
    float4 at1 = *(const float4*)(att + hl * 8 + 4);
    float4 bi0 = *(const float4*)(bias + hl * 8);
    float4 bi1 = *(const float4*)(bias + hl * 8 + 4);
#if defined(HAVE_FDOT2)
    f16x2 av0 = {(_Float16)(at0.x * L2E), (_Float16)(at0.y * L2E)};
    f16x2 av1 = {(_Float16)(at0.z * L2E), (_Float16)(at0.w * L2E)};
    f16x2 av2 = {(_Float16)(at1.x * L2E), (_Float16)(at1.y * L2E)};
    f16x2 av3 = {(_Float16)(at1.z * L2E), (_Float16)(at1.w * L2E)};
#else
    f32x8 avf = {at0.x * L2E, at0.y * L2E, at0.z * L2E, at0.w * L2E,
                 at1.x * L2E, at1.y * L2E, at1.z * L2E, at1.w * L2E};
#endif

    auto score = [&](f16x8 a_, f16x8 b4_) -> float {
        f16x8 t = a_ + b4_;
        f16x8 u = __builtin_elementwise_max(t, t * NS);
#if defined(HAVE_FDOT2)
        f16x2 u0 = __builtin_shufflevector(u, u, 0, 1);
        f16x2 u1 = __builtin_shufflevector(u, u, 2, 3);
        f16x2 u2 = __builtin_shufflevector(u, u, 4, 5);
        f16x2 u3 = __builtin_shufflevector(u, u, 6, 7);
        return __builtin_amdgcn_fdot2(u0, av0,
               __builtin_amdgcn_fdot2(u1, av1,
               __builtin_amdgcn_fdot2(u2, av2,
               __builtin_amdgcn_fdot2(u3, av3, 0.f, false), false), false), false);
#else
        f32x8 uf = cvt8(u);
        float pp = 0.f;
#pragma unroll
        for (int i = 0; i < 8; i++) pp += uf[i] * avf[i];
        return pp;
#endif
    };

    // 16-lane (or 8-lane for H==2) butterfly reduce, pure DPP.
    auto red = [&](float v) -> float {
        v = dpp_add<0xB1>(v);            // xor1
        v = dpp_add<0x4E>(v);            // xor2
        v = dpp_add<0x141>(v);           // xor4 (row_half_mirror)
        if (H == 1) v = dpp_add<0x140>(v);   // xor8 (row_mirror)
        return v;
    };

    const unsigned cap = (unsigned)(N - 1) << 8;
    auto ldoff = [&](int pos) -> unsigned {
        unsigned v = (unsigned)sorted_src[pos];
        return (v < cap) ? v : cap;
    };
    auto grow = [&](unsigned off) -> f16x8 {
        return *(const f16x8*)((const char*)xl + (size_t)(off + hl16));
    };

    // ---- current pair state (first pair: full chain) ----
    int n0 = 2 * p;
    bool has1 = (n0 + 1) < N;
    int n1 = has1 ? n0 + 1 : n0;
    int s00 = start[n0], M0 = deg[n0] + 1;
    int s01 = start[n1], M1 = deg[n1] + 1;

    for (;;) {
        // ---- prefetch next pair's start/deg (consumed after the loop) ----
        const int pn = p + stride;
        const bool hn = pn < npairs;
        const int nn0 = hn ? 2 * pn : n0;
        const bool nhas1 = (nn0 + 1) < N;
        const int nn1 = nhas1 ? nn0 + 1 : nn0;
        int ns00 = start[nn0], nM0 = deg[nn0] + 1;
        int ns01 = start[nn1], nM1 = deg[nn1] + 1;

        // b4 rows: independent loads, overlap the offset loads below
        const f16x8 b40 = *(const f16x8*)(xr + (size_t)n0 * 128 + hl * 8);
        const f16x8 b41 = *(const f16x8*)(xr + (size_t)n1 * 128 + hl * 8);

        const int Mmax = (M0 > M1) ? M0 : M1;
        const int K   = (Mmax + 3) >> 2;
        const int KK  = (K + 1) & ~1;      // pipeline pairs (>=2)

        f32x8 acc0 = {0.f, 0.f, 0.f, 0.f, 0.f, 0.f, 0.f, 0.f};
        f32x8 acc1 = {0.f, 0.f, 0.f, 0.f, 0.f, 0.f, 0.f, 0.f};
        float den0 = 0.f, den1 = 0.f;

        auto cone = [&](int kk, f16x8 a, f16x8 b4_, int M_, float& den_, f32x8& acc_) {
            float v = red(score(a, b4_));
            float e = (4 * kk + g < M_) ? FEXP2(v) : 0.f;
            den_ += e;
#pragma unroll
            for (int i = 0; i < 8; i++)
                acc_[i] = fmaf((float)a[i], e, acc_[i]);   // v_fma_mix
        };

        // 2-stage pipeline; group 0 specialized (self-loop in slot g==0)
        unsigned o00 = (g == 0) ? (unsigned)n0 << 8 : ldoff(s00 + g - 1);
        unsigned o01 = (g == 0) ? (unsigned)n1 << 8 : ldoff(s01 + g - 1);
        unsigned o10 = ldoff(s00 + g + 3);
        unsigned o11 = ldoff(s01 + g + 3);
        f16x8 c00 = grow(o00), c01 = grow(o01), c10 = grow(o10), c11 = grow(o11);
        for (int k = 2; k < KK; k += 2) {
            unsigned p00 = ldoff(s00 + 4 * k + g - 1);
            unsigned p01 = ldoff(s01 + 4 * k + g - 1);
            unsigned p10 = ldoff(s00 + 4 * k + g + 3);
            unsigned p11 = ldoff(s01 + 4 * k + g + 3);
            f16x8 d00 = grow(p00), d01 = grow(p01), d10 = grow(p10), d11 = grow(p11);
            cone(k - 2, c00, b40, M0, den0, acc0);
            cone(k - 2, c01, b41, M1, den1, acc1);
            cone(k - 1, c10, b40, M0, den0, acc0);
            cone(k - 1, c11, b41, M1, den1, acc1);
            c00 = d00; c01 = d01; c10 = d10; c11 = d11;
        }
        cone(KK - 2, c00, b40, M0, den0, acc0);
        cone(KK - 2, c01, b41, M1, den1, acc1);
        cone(KK - 1, c10, b40, M0, den0, acc0);
        cone(KK - 1, c11, b41, M1, den1, acc1);

        // combine the 4 edge-groups (feature-aligned): masks 16 and 32 only.
        den0 += __shfl_xor(den0, 16, 64);
        den0 += __shfl_xor(den0, 32, 64);
        den1 += __shfl_xor(den1, 16, 64);
        den1 += __shfl_xor(den1, 32, 64);
#pragma unroll
        for (int i = 0; i < 8; i++) {
            acc0[i] += __shfl_xor(acc0[i], 16, 64);
            acc0[i] += __shfl_xor(acc0[i], 32, 64);
            acc1[i] += __shfl_xor(acc1[i], 16, 64);
            acc1[i] += __shfl_xor(acc1[i], 32, 64);
        }

        // lanes 0-15 store node0, lanes 16-31 store node1 (parallel epilogue)
        const int which = lane >> 4;
        if (which == 0 || (which == 1 && has1)) {
            float inv = 1.0f / (which == 0 ? den0 : den1);
            int nodeo = (which == 0) ? n0 : n1;
            float o[8];
#pragma unroll
            for (int i = 0; i < 8; i++) {
                float a = (which == 0) ? acc0[i] : acc1[i];
                float b = (i < 4) ? ((i == 0) ? bi0.x : (i == 1) ? bi0.y : (i == 2) ? bi0.z : bi0.w)
                                  : ((i == 4) ? bi1.x : (i == 5) ? bi1.y : (i == 6) ? bi1.z : bi1.w);
                o[i] = a * inv + b;
            }
            if (BFOUT) {   // next layer's A: fp16 hi+lo split
                f16x8 hv, lv;
#pragma unroll
                for (int i = 0; i < 8; i++) {
                    _Float16 h = (_Float16)o[i];
                    hv[i] = h;
                    lv[i] = (_Float16)(o[i] - (float)h);
                }
                *(f16x8*)(oh + (size_t)nodeo * 128 + hl * 8) = hv;
                *(f16x8*)(ol + (size_t)nodeo * 128 + hl * 8) = lv;
            } else {
                *(float4*)(outf + (size_t)nodeo * 128 + hl * 8) =
                    make_float4(o[0], o[1], o[2], o[3]);
                *(float4*)(outf + (size_t)nodeo * 128 + hl * 8 + 4) =
                    make_float4(o[4], o[5], o[6], o[7]);
            }
        }

        if (!hn) break;
        p = pn; n0 = nn0; has1 = nhas1; n1 = nn1;
        s00 = ns00; M0 = nM0; s01 = ns01; M1 = nM1;
    }
}

// ---------------------------------------------------------------------------
extern "C" void kernel_launch(void* const* d_in, const int* in_sizes, int n_in,
                              void* d_out, int out_size, void* d_ws, size_t ws_size,
                              hipStream_t stream)
{
    const float* x    = (const float*)d_in[0];
    const int*   ei   = (const int*)d_in[1];
    const float* Wl1  = (const float*)d_in[3];
    const float* Wr1  = (const float*)d_in[4];
    const float* att1 = (const float*)d_in[5];
    const float* b1   = (const float*)d_in[6];
    const float* Wl2  = (const float*)d_in[7];
    const float* Wr2  = (const float*)d_in[8];
    const float* att2 = (const float*)d_in[9];
    const float* b2   = (const float*)d_in[10];
    float* out = (float*)d_out;

    const int N  = in_sizes[0] / 128;
    const int E  = in_sizes[1] / 2;
    const int NB = (N + NPB - 1) / NPB;

    const size_t nf = (size_t)N * 128;
    _Float16* xlf  = (_Float16*)d_ws;                 // nf fp16 (gather array)
    _Float16* xrf  = xlf + nf;                        // nf fp16
    _Float16* ah   = xrf + nf;                        // nf fp16 (A hi: x, then h)
    _Float16* al   = ah + nf;                         // nf fp16 (A lo)
    _Float16* wt   = al + nf;                         // 4*16384 fp16
    int* gcursor   = (int*)(wt + 4 * 16384);          // 256
    int* start     = gcursor + 256;                   // N
    int* deg       = start + N;                       // N
    size_t stgoff  = ((size_t)(deg + N) + 7) & ~(size_t)7;
    int2* staging  = (int2*)stgoff;                   // NB*BCAP int2 (padded)
    int* sorted_src = (int*)(staging + (size_t)NB * BCAP);  // NB*BCAP + 64 ints

    const int grid_chunk = (E + CHUNK - 1) / CHUNK;
    const int npairs     = (N + 1) / 2;
    int node_grid        = (npairs + 3) / 4;
    if (node_grid > 2048) node_grid = 2048;           // persistent grid-stride
    const int gemm_gx    = (N + 127) / 128;
    const int split_grid = (int)((nf / 2 + 255) / 256);

    // ---- zero bucket cursors (captured async op) ----
    hipMemsetAsync(gcursor, 0, 256 * sizeof(int), stream);

    // ---- K1: prep (W fp16-transpose, x hi/lo split) + chunk bucketing ----
    k1_prep_bucket_kernel<<<grid_chunk + 256 + split_grid, 256, 0, stream>>>(
        Wl1, Wr1, Wl2, Wr2, wt, x, ah, al, (int)nf,
        ei, gcursor, staging, E, grid_chunk);

    // ---- K2: per-bucket counting sort + layer-1 GEMM (both halves) ----
    k2_sort_gemm_kernel<<<NB + 2 * gemm_gx, 256, 0, stream>>>(
        staging, gcursor, start, deg, sorted_src, N, NB,
        ah, al, wt + 0 * 16384, wt + 1 * 16384, xlf, xrf, gemm_gx);

    // ---- Layer 1 fused ----
    gat_fused_kernel<2, true><<<node_grid, 256, 0, stream>>>(
        xlf, xrf, att1, b1, start, deg, sorted_src, nullptr, ah, al, N, npairs);

    // ---- Layer 2: GEMM + fused ----
    gemm_f16_kernel<<<dim3(gemm_gx, 2), 256, 0, stream>>>(
        ah, al, wt + 2 * 16384, wt + 3 * 16384, xlf, xrf, N);
    gat_fused_kernel<1, false><<<node_grid, 256, 0, stream>>>(
        xlf, xrf, att2, b2, start, deg, sorted_src, out, nullptr, nullptr, N, npairs);
}